// Round 1
// baseline (1811.316 us; speedup 1.0000x reference)
//
#include <hip/hip_runtime.h>

// Conv2d: B=32, IC=128, H=W=112 -> OC=256, K=3, stride=2, pad=1, OH=OW=56.
// Round 1: correct fp32 baseline. One thread per output pixel, 8 output
// channels per thread; per-block weight slice (8 oc x 128 ic x 9 taps) in LDS
// laid out [tap][oc8] so each tap read is 2x broadcast ds_read_b128.

#define B_    32
#define IC_   128
#define H_    112
#define W_    112
#define OC_   256
#define OH_   56
#define OW_   56
#define TPB   256
#define OCPT  8

__global__ __launch_bounds__(TPB) void conv2d_f32_kernel(
    const float* __restrict__ x, const float* __restrict__ w,
    const float* __restrict__ bias, float* __restrict__ out) {
  __shared__ float wlds[IC_ * 9][OCPT];  // 1152 * 8 * 4B = 36 KiB

  const int b   = blockIdx.z;
  const int oc0 = blockIdx.y * OCPT;

  // Cooperative stage of the 8-channel weight slice.
  // Global reads coalesced along t (contiguous per channel); LDS layout [t][j].
  const float* wsrc = w + (size_t)oc0 * (IC_ * 9);
  for (int i = threadIdx.x; i < IC_ * 9 * OCPT; i += TPB) {
    const int j = i / (IC_ * 9);
    const int t = i - j * (IC_ * 9);
    wlds[t][j] = wsrc[(size_t)j * (IC_ * 9) + t];
  }
  __syncthreads();

  const int p  = blockIdx.x * TPB + threadIdx.x;
  const int ow = p % OW_;
  const int oh = p / OW_;
  const bool pv = (oh < OH_);          // tail guard (3136 = 12.25 * 256)

  const int ih0 = 2 * oh - 1;          // pad=1, stride=2: taps hit ih0..ih0+2
  const int iw0 = 2 * ow - 1;          // only index -1 can be out of bounds
  const float* xb = x + (size_t)b * IC_ * H_ * W_
                      + (ptrdiff_t)ih0 * W_ + iw0;

  float acc[OCPT];
#pragma unroll
  for (int j = 0; j < OCPT; ++j) acc[j] = 0.f;

  for (int ic = 0; ic < IC_; ++ic) {
    const float* xc = xb + (size_t)ic * (H_ * W_);
#pragma unroll
    for (int kh = 0; kh < 3; ++kh) {
      const int ih = ih0 + kh;
      const bool hv = pv && (ih >= 0);
#pragma unroll
      for (int kw = 0; kw < 3; ++kw) {
        const bool v = hv && ((iw0 + kw) >= 0);
        const float xv = v ? xc[kh * W_ + kw] : 0.f;
        const int t = ic * 9 + kh * 3 + kw;
        const float4 w0 = *reinterpret_cast<const float4*>(&wlds[t][0]);
        const float4 w1 = *reinterpret_cast<const float4*>(&wlds[t][4]);
        acc[0] = fmaf(xv, w0.x, acc[0]);
        acc[1] = fmaf(xv, w0.y, acc[1]);
        acc[2] = fmaf(xv, w0.z, acc[2]);
        acc[3] = fmaf(xv, w0.w, acc[3]);
        acc[4] = fmaf(xv, w1.x, acc[4]);
        acc[5] = fmaf(xv, w1.y, acc[5]);
        acc[6] = fmaf(xv, w1.z, acc[6]);
        acc[7] = fmaf(xv, w1.w, acc[7]);
      }
    }
  }

  if (pv) {
#pragma unroll
    for (int j = 0; j < OCPT; ++j) {
      const size_t oidx =
          (((size_t)(b * OC_ + oc0 + j)) * OH_ + oh) * OW_ + ow;
      out[oidx] = acc[j] + bias[oc0 + j];
    }
  }
}

extern "C" void kernel_launch(void* const* d_in, const int* in_sizes, int n_in,
                              void* d_out, int out_size, void* d_ws, size_t ws_size,
                              hipStream_t stream) {
  const float* x    = (const float*)d_in[0];
  const float* w    = (const float*)d_in[1];
  const float* bias = (const float*)d_in[2];
  float* out        = (float*)d_out;

  dim3 grid((OH_ * OW_ + TPB - 1) / TPB, OC_ / OCPT, B_);
  conv2d_f32_kernel<<<grid, dim3(TPB), 0, stream>>>(x, w, bias, out);
}

// Round 2
// 192.462 us; speedup vs baseline: 9.4113x; 9.4113x over previous
//
#include <hip/hip_runtime.h>
#include <hip/hip_bf16.h>

// Conv2d B=32 IC=128 112x112 -> OC=256, K=3, s=2, p=1 (OH=OW=56).
// Round 2: bf16 MFMA implicit GEMM.
//   k1: x NCHW f32 -> xt[b][113][113][128] bf16 (zero-padded top/left) in d_ws
//   k2: w OIHW f32 -> wt[tap][oc][ic] bf16 in d_ws
//   k3: GEMM M=oc(256) x N=pix(100352) x K=9*128, m97-style 128x128 tile,
//       BK=32, 4 waves x 64x64, global_load_lds(16B) into linear LDS.
// Fallback to fp32 direct kernel if ws too small.

#define B_    32
#define IC_   128
#define H_    112
#define W_    112
#define OC_   256
#define OH_   56
#define OW_   56
#define HP    113
#define NPIX  (B_ * OH_ * OW_)          // 100352
#define XT_BYTES ((size_t)B_ * HP * HP * IC_ * 2)   // 104,603,648
#define WT_BYTES ((size_t)9 * OC_ * IC_ * 2)        // 589,824

typedef __attribute__((ext_vector_type(8))) short bf16x8;
typedef __attribute__((ext_vector_type(4))) float f32x4;

static __device__ __forceinline__ unsigned short f2bf(float f) {
  union { float f; unsigned u; } v; v.f = f;
  unsigned r = v.u + 0x7FFF + ((v.u >> 16) & 1);   // RNE; inputs finite
  return (unsigned short)(r >> 16);
}

// ---------------- k1: x -> padded channels-last bf16 ----------------
__global__ __launch_bounds__(256) void xtrans_kernel(
    const float* __restrict__ x, unsigned short* __restrict__ xt) {
  __shared__ float lds[112][33];
  const int ihp = blockIdx.x;            // 0..112 (0 is the zero pad row)
  const int icb = blockIdx.y;            // 0..3  (32-channel slice)
  const int b   = blockIdx.z;
  const int tid = threadIdx.x;

  if (ihp > 0) {
    const int ih = ihp - 1;
    const float* xp = x + ((size_t)(b * IC_ + icb * 32) * H_ + ih) * W_;
    for (int i = tid; i < 32 * 112; i += 256) {
      const int ic = i / 112;
      const int iw = i - ic * 112;
      lds[iw][ic] = xp[(size_t)ic * (H_ * W_) + iw];
    }
  }
  __syncthreads();

  unsigned short* xrow = xt + ((size_t)(b * HP + ihp)) * HP * IC_ + icb * 32;
  for (int i = tid; i < 113 * 16; i += 256) {
    const int iwp = i >> 4;
    const int icp = i & 15;
    unsigned v = 0;
    if (ihp > 0 && iwp > 0) {
      const unsigned lo = f2bf(lds[iwp - 1][2 * icp]);
      const unsigned hi = f2bf(lds[iwp - 1][2 * icp + 1]);
      v = lo | (hi << 16);
    }
    *reinterpret_cast<unsigned*>(xrow + (size_t)iwp * IC_ + icp * 2) = v;
  }
}

// ---------------- k2: w -> wt[tap][oc][ic] bf16 ----------------
__global__ __launch_bounds__(256) void wtrans_kernel(
    const float* __restrict__ w, unsigned short* __restrict__ wt) {
  const int t  = blockIdx.x * 256 + threadIdx.x;   // 0..32767 == oc*128+ic
  const int oc = t >> 7;
  const int ic = t & 127;
  const float* ws = w + (size_t)t * 9;             // w[oc][ic][*]
#pragma unroll
  for (int tap = 0; tap < 9; ++tap)
    wt[((size_t)tap * OC_ + oc) * IC_ + ic] = f2bf(ws[tap]);
}

// ---------------- k3: MFMA implicit GEMM ----------------
__global__ __launch_bounds__(256) void conv_mfma_kernel(
    const unsigned short* __restrict__ xt, const unsigned short* __restrict__ wt,
    const float* __restrict__ bias, float* __restrict__ out) {
  __shared__ short Ws[128 * 32];   // [oc_row][ic] 8 KiB
  __shared__ short Xs[128 * 32];   // [pix_row][ic] 8 KiB

  const int tid  = threadIdx.x;
  const int wav  = tid >> 6;
  const int lane = tid & 63;

  const int mt  = blockIdx.x & 1;      // oc tile (fast index: L2 reuse of X)
  const int pt  = blockIdx.x >> 1;     // pixel tile
  const int oc0 = mt * 128;
  const int p0  = pt * 128;

  // --- staging addresses: wave w stages rows [w*32, w*32+32) of each tile ---
  const int l2 = lane >> 2;            // row within 16-row group
  const int lc = lane & 3;             // 16B chunk within 64B row
  const char* xsrc[2];
  const char* wsrc[2];
#pragma unroll
  for (int i = 0; i < 2; ++i) {
    const int pix = p0 + wav * 32 + i * 16 + l2;
    const int b   = pix / 3136;
    const int q   = pix - b * 3136;
    const int oh  = q / 56;
    const int ow  = q - oh * 56;
    const size_t e = (((size_t)b * HP + 2 * oh) * HP + 2 * ow) * IC_;
    xsrc[i] = reinterpret_cast<const char*>(xt) + e * 2 + lc * 16;
    const int ocr = oc0 + wav * 32 + i * 16 + l2;
    wsrc[i] = reinterpret_cast<const char*>(wt) + (size_t)ocr * IC_ * 2 + lc * 16;
  }
  char* xdst = reinterpret_cast<char*>(Xs) + wav * 2048;
  char* wdst = reinterpret_cast<char*>(Ws) + wav * 2048;

  // --- fragment read bases ---
  const int wm  = wav >> 1;            // oc half of tile
  const int wn  = wav & 1;             // pixel half of tile
  const int l15 = lane & 15;
  const int kg  = (lane >> 4) * 8;     // k element offset
  const short* wrow = Ws + ((wm * 64 + l15) * 32 + kg);
  const short* xrow = Xs + ((wn * 64 + l15) * 32 + kg);

  f32x4 acc[4][4] = {};

  for (int tap = 0; tap < 9; ++tap) {
    const int kh = tap / 3;
    const int kw = tap - kh * 3;
    const size_t xtap = ((size_t)(kh * HP + kw)) * IC_ * 2;
    const size_t wtap = (size_t)tap * OC_ * IC_ * 2;
#pragma unroll
    for (int icc = 0; icc < 4; ++icc) {
      const size_t xoff = xtap + (size_t)icc * 64;
      const size_t woff = wtap + (size_t)icc * 64;
      __syncthreads();   // previous step's LDS reads complete
#pragma unroll
      for (int i = 0; i < 2; ++i) {
        __builtin_amdgcn_global_load_lds(
            (const __attribute__((address_space(1))) void*)(xsrc[i] + xoff),
            (__attribute__((address_space(3))) void*)(xdst + i * 1024), 16, 0, 0);
        __builtin_amdgcn_global_load_lds(
            (const __attribute__((address_space(1))) void*)(wsrc[i] + woff),
            (__attribute__((address_space(3))) void*)(wdst + i * 1024), 16, 0, 0);
      }
      __syncthreads();   // staging complete (compiler drains vmcnt)

      bf16x8 af[4], bfr[4];
#pragma unroll
      for (int mi = 0; mi < 4; ++mi)
        af[mi] = *reinterpret_cast<const bf16x8*>(wrow + mi * 16 * 32);
#pragma unroll
      for (int ni = 0; ni < 4; ++ni)
        bfr[ni] = *reinterpret_cast<const bf16x8*>(xrow + ni * 16 * 32);
#pragma unroll
      for (int mi = 0; mi < 4; ++mi)
#pragma unroll
        for (int ni = 0; ni < 4; ++ni)
          acc[mi][ni] = __builtin_amdgcn_mfma_f32_16x16x32_bf16(
              af[mi], bfr[ni], acc[mi][ni], 0, 0, 0);
    }
  }

  // --- epilogue: D[oc][pix]; lanes sweep pixels -> coalesced ---
#pragma unroll
  for (int mi = 0; mi < 4; ++mi) {
#pragma unroll
    for (int j = 0; j < 4; ++j) {
      const int oc = oc0 + wm * 64 + mi * 16 + (lane >> 4) * 4 + j;
      const float bv = bias[oc];
#pragma unroll
      for (int ni = 0; ni < 4; ++ni) {
        const int pix = p0 + wn * 64 + ni * 16 + l15;
        const int b   = pix / 3136;
        const int q   = pix - b * 3136;
        out[((size_t)b * OC_ + oc) * 3136 + q] = acc[mi][ni][j] + bv;
      }
    }
  }
}

// ---------------- fallback: round-1 fp32 direct conv ----------------
__global__ __launch_bounds__(256) void conv2d_f32_kernel(
    const float* __restrict__ x, const float* __restrict__ w,
    const float* __restrict__ bias, float* __restrict__ out) {
  __shared__ float wlds[IC_ * 9][8];
  const int b   = blockIdx.z;
  const int oc0 = blockIdx.y * 8;
  const float* wsrc = w + (size_t)oc0 * (IC_ * 9);
  for (int i = threadIdx.x; i < IC_ * 9 * 8; i += 256) {
    const int j = i / (IC_ * 9);
    const int t = i - j * (IC_ * 9);
    wlds[t][j] = wsrc[(size_t)j * (IC_ * 9) + t];
  }
  __syncthreads();
  const int p  = blockIdx.x * 256 + threadIdx.x;
  const int ow = p % OW_;
  const int oh = p / OW_;
  const bool pv = (oh < OH_);
  const int ih0 = 2 * oh - 1;
  const int iw0 = 2 * ow - 1;
  const float* xb = x + (size_t)b * IC_ * H_ * W_ + (ptrdiff_t)ih0 * W_ + iw0;
  float acc[8];
#pragma unroll
  for (int j = 0; j < 8; ++j) acc[j] = 0.f;
  for (int ic = 0; ic < IC_; ++ic) {
    const float* xc = xb + (size_t)ic * (H_ * W_);
#pragma unroll
    for (int kh = 0; kh < 3; ++kh) {
      const bool hv = pv && ((ih0 + kh) >= 0);
#pragma unroll
      for (int kw = 0; kw < 3; ++kw) {
        const bool v = hv && ((iw0 + kw) >= 0);
        const float xv = v ? xc[kh * W_ + kw] : 0.f;
        const int t = ic * 9 + kh * 3 + kw;
        const float4 w0 = *reinterpret_cast<const float4*>(&wlds[t][0]);
        const float4 w1 = *reinterpret_cast<const float4*>(&wlds[t][4]);
        acc[0] = fmaf(xv, w0.x, acc[0]); acc[1] = fmaf(xv, w0.y, acc[1]);
        acc[2] = fmaf(xv, w0.z, acc[2]); acc[3] = fmaf(xv, w0.w, acc[3]);
        acc[4] = fmaf(xv, w1.x, acc[4]); acc[5] = fmaf(xv, w1.y, acc[5]);
        acc[6] = fmaf(xv, w1.z, acc[6]); acc[7] = fmaf(xv, w1.w, acc[7]);
      }
    }
  }
  if (pv) {
#pragma unroll
    for (int j = 0; j < 8; ++j)
      out[(((size_t)(b * OC_ + oc0 + j)) * OH_ + oh) * OW_ + ow] =
          acc[j] + bias[oc0 + j];
  }
}

extern "C" void kernel_launch(void* const* d_in, const int* in_sizes, int n_in,
                              void* d_out, int out_size, void* d_ws, size_t ws_size,
                              hipStream_t stream) {
  const float* x    = (const float*)d_in[0];
  const float* w    = (const float*)d_in[1];
  const float* bias = (const float*)d_in[2];
  float* out        = (float*)d_out;

  if (ws_size >= XT_BYTES + WT_BYTES) {
    unsigned short* xt  = (unsigned short*)d_ws;
    unsigned short* wtp = (unsigned short*)((char*)d_ws + XT_BYTES);
    xtrans_kernel<<<dim3(HP, 4, B_), 256, 0, stream>>>(x, xt);
    wtrans_kernel<<<128, 256, 0, stream>>>(w, wtp);
    conv_mfma_kernel<<<(NPIX / 128) * 2, 256, 0, stream>>>(xt, wtp, bias, out);
  } else {
    conv2d_f32_kernel<<<dim3(13, OC_ / 8, B_), 256, 0, stream>>>(x, w, bias, out);
  }
}

// Round 3
// 159.431 us; speedup vs baseline: 11.3612x; 1.2072x over previous
//
#include <hip/hip_runtime.h>
#include <hip/hip_bf16.h>

// Conv2d B=32 IC=128 112x112 -> OC=256, K=3, s=2, p=1 (OH=OW=56).
// Round 3: same implicit-GEMM plan, rewritten xtrans:
//   - one block per (b, padded-row): float4 coalesced loads, bf16 cvt,
//     XOR-swizzled LDS [ic][iw], transposed gather, uint4 coalesced stores.
//   k3 GEMM unchanged (m97-style 128x128, BK=32, global_load_lds 16B).

#define B_    32
#define IC_   128
#define H_    112
#define W_    112
#define HW_   (H_ * W_)
#define OC_   256
#define OH_   56
#define OW_   56
#define HP    113
#define NPIX  (B_ * OH_ * OW_)          // 100352
#define XT_BYTES ((size_t)B_ * HP * HP * IC_ * 2)   // 104,603,648
#define WT_BYTES ((size_t)9 * OC_ * IC_ * 2)        // 589,824

typedef __attribute__((ext_vector_type(8))) short bf16x8;
typedef __attribute__((ext_vector_type(4))) float f32x4;

static __device__ __forceinline__ unsigned f2bf_u(float f) {
  union { float f; unsigned u; } v; v.f = f;
  return (v.u + 0x7FFF + ((v.u >> 16) & 1)) >> 16;   // RNE; inputs finite
}

// ---------------- k1: x -> padded channels-last bf16 ----------------
// Block (ihp, b). LDS holds one input row across all 128 channels as bf16,
// layout [ic][iw] in 8B granules, column-swizzled: g' = g ^ (((ic>>3)&7)<<2).
__global__ __launch_bounds__(256) void xtrans_kernel(
    const float* __restrict__ x, unsigned short* __restrict__ xt) {
  __shared__ unsigned short lds[128 * 128];   // 32 KiB, row stride 128 ush
  const int ihp = blockIdx.x;                 // 0..112 (0 = zero pad row)
  const int b   = blockIdx.y;
  const int tid = threadIdx.x;

  if (ihp > 0) {
    const float* xp = x + (size_t)b * IC_ * HW_ + (size_t)(ihp - 1) * W_;
#pragma unroll
    for (int it = 0; it < 16; ++it) {
      const int i  = tid + it * 256;          // (ic, g) over 128 x 32
      const int ic = i >> 5;
      const int g  = i & 31;                  // 16B granule along iw
      if (g < 28) {
        const float4 v = *reinterpret_cast<const float4*>(
            xp + (size_t)ic * HW_ + g * 4);
        uint2 p;
        p.x = f2bf_u(v.x) | (f2bf_u(v.y) << 16);
        p.y = f2bf_u(v.z) | (f2bf_u(v.w) << 16);
        const int gs = g ^ (((ic >> 3) & 7) << 2);
        *reinterpret_cast<uint2*>(&lds[ic * 128 + gs * 4]) = p;
      }
    }
  }
  __syncthreads();

  unsigned short* xrow = xt + ((size_t)(b * HP + ihp)) * (HP * IC_);
  const bool live = (ihp > 0);
#pragma unroll
  for (int it = 0; it < 8; ++it) {
    const int e = tid + it * 256;             // (iwp, icg) over 113 x 16
    if (e >= HP * 16) break;
    const int iwp = e >> 4;
    const int icg = e & 15;
    uint4 v = {0u, 0u, 0u, 0u};
    if (live && iwp > 0) {
      const int iw  = iwp - 1;
      const int col = ((iw >> 2) ^ ((icg & 7) << 2)) * 4 + (iw & 3);
      const int r0  = icg * 8;
      unsigned u0 = lds[(r0 + 0) * 128 + col];
      unsigned u1 = lds[(r0 + 1) * 128 + col];
      unsigned u2 = lds[(r0 + 2) * 128 + col];
      unsigned u3 = lds[(r0 + 3) * 128 + col];
      unsigned u4 = lds[(r0 + 4) * 128 + col];
      unsigned u5 = lds[(r0 + 5) * 128 + col];
      unsigned u6 = lds[(r0 + 6) * 128 + col];
      unsigned u7 = lds[(r0 + 7) * 128 + col];
      v.x = u0 | (u1 << 16);
      v.y = u2 | (u3 << 16);
      v.z = u4 | (u5 << 16);
      v.w = u6 | (u7 << 16);
    }
    *reinterpret_cast<uint4*>(xrow + iwp * IC_ + icg * 8) = v;
  }
}

// ---------------- k2: w -> wt[tap][oc][ic] bf16 ----------------
__global__ __launch_bounds__(256) void wtrans_kernel(
    const float* __restrict__ w, unsigned short* __restrict__ wt) {
  const int t  = blockIdx.x * 256 + threadIdx.x;   // 0..32767 == oc*128+ic
  const int oc = t >> 7;
  const int ic = t & 127;
  const float* ws = w + (size_t)t * 9;             // w[oc][ic][*]
#pragma unroll
  for (int tap = 0; tap < 9; ++tap)
    wt[((size_t)tap * OC_ + oc) * IC_ + ic] = (unsigned short)f2bf_u(ws[tap]);
}

// ---------------- k3: MFMA implicit GEMM ----------------
__global__ __launch_bounds__(256) void conv_mfma_kernel(
    const unsigned short* __restrict__ xt, const unsigned short* __restrict__ wt,
    const float* __restrict__ bias, float* __restrict__ out) {
  __shared__ short Ws[128 * 32];   // [oc_row][ic] 8 KiB
  __shared__ short Xs[128 * 32];   // [pix_row][ic] 8 KiB

  const int tid  = threadIdx.x;
  const int wav  = tid >> 6;
  const int lane = tid & 63;

  const int mt  = blockIdx.x & 1;      // oc tile (fast index: L2 reuse of X)
  const int pt  = blockIdx.x >> 1;     // pixel tile
  const int oc0 = mt * 128;
  const int p0  = pt * 128;

  const int l2 = lane >> 2;            // row within 16-row group
  const int lc = lane & 3;             // 16B chunk within 64B row
  const char* xsrc[2];
  const char* wsrc[2];
#pragma unroll
  for (int i = 0; i < 2; ++i) {
    const int pix = p0 + wav * 32 + i * 16 + l2;
    const int b   = pix / 3136;
    const int q   = pix - b * 3136;
    const int oh  = q / 56;
    const int ow  = q - oh * 56;
    const size_t e = (((size_t)b * HP + 2 * oh) * HP + 2 * ow) * IC_;
    xsrc[i] = reinterpret_cast<const char*>(xt) + e * 2 + lc * 16;
    const int ocr = oc0 + wav * 32 + i * 16 + l2;
    wsrc[i] = reinterpret_cast<const char*>(wt) + (size_t)ocr * IC_ * 2 + lc * 16;
  }
  char* xdst = reinterpret_cast<char*>(Xs) + wav * 2048;
  char* wdst = reinterpret_cast<char*>(Ws) + wav * 2048;

  const int wm  = wav >> 1;
  const int wn  = wav & 1;
  const int l15 = lane & 15;
  const int kg  = (lane >> 4) * 8;
  const short* wrow = Ws + ((wm * 64 + l15) * 32 + kg);
  const short* xrow = Xs + ((wn * 64 + l15) * 32 + kg);

  f32x4 acc[4][4] = {};

  for (int tap = 0; tap < 9; ++tap) {
    const int kh = tap / 3;
    const int kw = tap - kh * 3;
    const size_t xtap = ((size_t)(kh * HP + kw)) * IC_ * 2;
    const size_t wtap = (size_t)tap * OC_ * IC_ * 2;
#pragma unroll
    for (int icc = 0; icc < 4; ++icc) {
      const size_t xoff = xtap + (size_t)icc * 64;
      const size_t woff = wtap + (size_t)icc * 64;
      __syncthreads();
#pragma unroll
      for (int i = 0; i < 2; ++i) {
        __builtin_amdgcn_global_load_lds(
            (const __attribute__((address_space(1))) void*)(xsrc[i] + xoff),
            (__attribute__((address_space(3))) void*)(xdst + i * 1024), 16, 0, 0);
        __builtin_amdgcn_global_load_lds(
            (const __attribute__((address_space(1))) void*)(wsrc[i] + woff),
            (__attribute__((address_space(3))) void*)(wdst + i * 1024), 16, 0, 0);
      }
      __syncthreads();

      bf16x8 af[4], bfr[4];
#pragma unroll
      for (int mi = 0; mi < 4; ++mi)
        af[mi] = *reinterpret_cast<const bf16x8*>(wrow + mi * 16 * 32);
#pragma unroll
      for (int ni = 0; ni < 4; ++ni)
        bfr[ni] = *reinterpret_cast<const bf16x8*>(xrow + ni * 16 * 32);
#pragma unroll
      for (int mi = 0; mi < 4; ++mi)
#pragma unroll
        for (int ni = 0; ni < 4; ++ni)
          acc[mi][ni] = __builtin_amdgcn_mfma_f32_16x16x32_bf16(
              af[mi], bfr[ni], acc[mi][ni], 0, 0, 0);
    }
  }

#pragma unroll
  for (int mi = 0; mi < 4; ++mi) {
#pragma unroll
    for (int j = 0; j < 4; ++j) {
      const int oc = oc0 + wm * 64 + mi * 16 + (lane >> 4) * 4 + j;
      const float bv = bias[oc];
#pragma unroll
      for (int ni = 0; ni < 4; ++ni) {
        const int pix = p0 + wn * 64 + ni * 16 + l15;
        const int b   = pix / 3136;
        const int q   = pix - b * 3136;
        out[((size_t)b * OC_ + oc) * 3136 + q] = acc[mi][ni][j] + bv;
      }
    }
  }
}

// ---------------- fallback: fp32 direct conv ----------------
__global__ __launch_bounds__(256) void conv2d_f32_kernel(
    const float* __restrict__ x, const float* __restrict__ w,
    const float* __restrict__ bias, float* __restrict__ out) {
  __shared__ float wlds[IC_ * 9][8];
  const int b   = blockIdx.z;
  const int oc0 = blockIdx.y * 8;
  const float* wsrc = w + (size_t)oc0 * (IC_ * 9);
  for (int i = threadIdx.x; i < IC_ * 9 * 8; i += 256) {
    const int j = i / (IC_ * 9);
    const int t = i - j * (IC_ * 9);
    wlds[t][j] = wsrc[(size_t)j * (IC_ * 9) + t];
  }
  __syncthreads();
  const int p  = blockIdx.x * 256 + threadIdx.x;
  const int ow = p % OW_;
  const int oh = p / OW_;
  const bool pv = (oh < OH_);
  const int ih0 = 2 * oh - 1;
  const int iw0 = 2 * ow - 1;
  const float* xb = x + (size_t)b * IC_ * HW_ + (ptrdiff_t)ih0 * W_ + iw0;
  float acc[8];
#pragma unroll
  for (int j = 0; j < 8; ++j) acc[j] = 0.f;
  for (int ic = 0; ic < IC_; ++ic) {
    const float* xc = xb + (size_t)ic * HW_;
#pragma unroll
    for (int kh = 0; kh < 3; ++kh) {
      const bool hv = pv && ((ih0 + kh) >= 0);
#pragma unroll
      for (int kw = 0; kw < 3; ++kw) {
        const bool v = hv && ((iw0 + kw) >= 0);
        const float xv = v ? xc[kh * W_ + kw] : 0.f;
        const int t = ic * 9 + kh * 3 + kw;
        const float4 w0 = *reinterpret_cast<const float4*>(&wlds[t][0]);
        const float4 w1 = *reinterpret_cast<const float4*>(&wlds[t][4]);
        acc[0] = fmaf(xv, w0.x, acc[0]); acc[1] = fmaf(xv, w0.y, acc[1]);
        acc[2] = fmaf(xv, w0.z, acc[2]); acc[3] = fmaf(xv, w0.w, acc[3]);
        acc[4] = fmaf(xv, w1.x, acc[4]); acc[5] = fmaf(xv, w1.y, acc[5]);
        acc[6] = fmaf(xv, w1.z, acc[6]); acc[7] = fmaf(xv, w1.w, acc[7]);
      }
    }
  }
  if (pv) {
#pragma unroll
    for (int j = 0; j < 8; ++j)
      out[(((size_t)(b * OC_ + oc0 + j)) * OH_ + oh) * OW_ + ow] =
          acc[j] + bias[oc0 + j];
  }
}

extern "C" void kernel_launch(void* const* d_in, const int* in_sizes, int n_in,
                              void* d_out, int out_size, void* d_ws, size_t ws_size,
                              hipStream_t stream) {
  const float* x    = (const float*)d_in[0];
  const float* w    = (const float*)d_in[1];
  const float* bias = (const float*)d_in[2];
  float* out        = (float*)d_out;

  if (ws_size >= XT_BYTES + WT_BYTES) {
    unsigned short* xt  = (unsigned short*)d_ws;
    unsigned short* wtp = (unsigned short*)((char*)d_ws + XT_BYTES);
    xtrans_kernel<<<dim3(HP, B_), 256, 0, stream>>>(x, xt);
    wtrans_kernel<<<128, 256, 0, stream>>>(w, wtp);
    conv_mfma_kernel<<<(NPIX / 128) * 2, 256, 0, stream>>>(xt, wtp, bias, out);
  } else {
    conv2d_f32_kernel<<<dim3(13, OC_ / 8, B_), 256, 0, stream>>>(x, w, bias, out);
  }
}